// Round 7
// baseline (964.264 us; speedup 1.0000x reference)
//
#include <hip/hip_runtime.h>
#include <hip/hip_bf16.h>
#include <math.h>

// Dims (fixed by the problem)
#define Bd 32
#define Sd 256
#define Ld 24
#define Ed 300
#define Hd 256
#define Td 16
#define Dd 256
#define EP 320    // E padded to multiple of 32
#define HPAD 264  // 256 + 8: pad A-tile row stride (528 B) to break 16-way LDS bank conflicts

using short8 = __attribute__((ext_vector_type(8))) short;
using f32x4  = __attribute__((ext_vector_type(4))) float;

// fast transcendentals (v_exp_f32 path; saturate correctly at +-inf)
__device__ __forceinline__ float fsigm(float x) { return 1.f / (1.f + __expf(-x)); }
__device__ __forceinline__ float ftanh(float x) {
  float e = __expf(2.f * x);
  return 1.f - 2.f / (e + 1.f);
}

// ---------------------------------------------------------------------------
// 1. sentence means: A_pad[r][k] = bf16(mean_w emb[word_ids[r][w]][k]), k<300, else 0
// grid 8192, block 320. emb is FLOAT32.
__global__ void sent_means_kernel(const int* __restrict__ wids,
                                  const float* __restrict__ emb,
                                  __hip_bfloat16* __restrict__ apad) {
  int r = blockIdx.x;
  __shared__ int ids[Ld];
  int tid = threadIdx.x;
  if (tid < Ld) ids[tid] = wids[r * Ld + tid];
  __syncthreads();
  float acc = 0.f;
  if (tid < Ed) {
#pragma unroll
    for (int w = 0; w < Ld; ++w) acc += emb[(size_t)ids[w] * Ed + tid];
    acc *= (1.f / 24.f);
  }
  apad[r * EP + tid] = __float2bfloat16(tid < Ed ? acc : 0.f);
}

// ---------------------------------------------------------------------------
// 2. weight prep (all sources FLOAT32 -> bf16 for MFMA)
__global__ void pad_wih_kernel(const float* __restrict__ src,
                               __hip_bfloat16* __restrict__ dst) {
  int i = blockIdx.x * 256 + threadIdx.x;   // 768*320
  if (i >= 768 * EP) return;
  int n = i / EP, k = i % EP;
  dst[i] = __float2bfloat16(k < Ed ? src[n * Ed + k] : 0.f);
}
__global__ void f2bf_kernel(const float* __restrict__ src,
                            __hip_bfloat16* __restrict__ dst, int n) {
  int i = blockIdx.x * 256 + threadIdx.x;
  if (i < n) dst[i] = __float2bfloat16(src[i]);
}
__global__ void transpose_att_kernel(const float* __restrict__ src,
                                     __hip_bfloat16* __restrict__ dst) {
  int i = blockIdx.x * 256 + threadIdx.x;   // 1024*1024: dst[n][k] = src[k][n]
  int n = i >> 10, k = i & 1023;
  dst[i] = __float2bfloat16(src[k * 1024 + n]);
}
__global__ void transpose_dna_kernel(const float* __restrict__ src,
                                     __hip_bfloat16* __restrict__ dst) {
  int i = blockIdx.x * 256 + threadIdx.x;   // 256*1024: dst[n][k] = src[k][n]
  int n = i >> 10, k = i & 1023;
  dst[i] = __float2bfloat16(src[k * Dd + n]);
}

// ---------------------------------------------------------------------------
// 3. MFMA GEMM: C[M,N] = A[M,K] @ W[N,K]^T (+bias[n]); A,W bf16 row-major, C fp32.
__global__ __launch_bounds__(256) void gemm_xwt_kernel(
    const __hip_bfloat16* __restrict__ A, int lda,
    const __hip_bfloat16* __restrict__ W, int ldw,
    float* __restrict__ C, int ldc,
    int M, int N, int K,
    const float* __restrict__ bias) {
  __shared__ unsigned short la[64][32];
  __shared__ unsigned short lb[64][32];
  const int tid = threadIdx.x;
  const int m0 = blockIdx.x * 64, n0 = blockIdx.y * 64;
  const int lane = tid & 63, wid = tid >> 6;
  const int wm = (wid >> 1) * 32, wn = (wid & 1) * 32;
  const int lrow = tid >> 2, lcol = (tid & 3) * 8;
  f32x4 acc00 = {0.f, 0.f, 0.f, 0.f}, acc01 = {0.f, 0.f, 0.f, 0.f};
  f32x4 acc10 = {0.f, 0.f, 0.f, 0.f}, acc11 = {0.f, 0.f, 0.f, 0.f};
  int arow = m0 + lrow; if (arow > M - 1) arow = M - 1;
  const int brow = n0 + lrow;
  const int fr = lane & 15, fq = (lane >> 4) * 8;
  for (int k0 = 0; k0 < K; k0 += 32) {
    uint4 av = *(const uint4*)(A + (size_t)arow * lda + k0 + lcol);
    uint4 bv = *(const uint4*)(W + (size_t)brow * ldw + k0 + lcol);
    *(uint4*)(&la[lrow][lcol]) = av;
    *(uint4*)(&lb[lrow][lcol]) = bv;
    __syncthreads();
    short8 a0 = *(const short8*)(&la[wm + fr][fq]);
    short8 a1 = *(const short8*)(&la[wm + 16 + fr][fq]);
    short8 b0 = *(const short8*)(&lb[wn + fr][fq]);
    short8 b1 = *(const short8*)(&lb[wn + 16 + fr][fq]);
    acc00 = __builtin_amdgcn_mfma_f32_16x16x32_bf16(a0, b0, acc00, 0, 0, 0);
    acc01 = __builtin_amdgcn_mfma_f32_16x16x32_bf16(a0, b1, acc01, 0, 0, 0);
    acc10 = __builtin_amdgcn_mfma_f32_16x16x32_bf16(a1, b0, acc10, 0, 0, 0);
    acc11 = __builtin_amdgcn_mfma_f32_16x16x32_bf16(a1, b1, acc11, 0, 0, 0);
    __syncthreads();
  }
  const int rq = (lane >> 4) * 4;
  f32x4 accs[2][2] = {{acc00, acc01}, {acc10, acc11}};
  for (int i = 0; i < 2; ++i)
    for (int j = 0; j < 2; ++j) {
      int n = n0 + wn + j * 16 + fr;
      float bv = bias ? bias[n] : 0.f;
      for (int r2 = 0; r2 < 4; ++r2) {
        int m = m0 + wm + i * 16 + rq + r2;
        if (m < M) C[(size_t)m * ldc + n] = accs[i][j][r2] + bv;
      }
    }
}

// ---------------------------------------------------------------------------
// 4. Persistent-weight MFMA GRU v3. grid 64 (dir=blk>>5, b=blk&31), block 512.
// Wave w owns h-dims [32w,32w+32): bfrag covers {r,z,n}x{2 halves} subtiles, so
// gate outputs land in the wave's own acc regs (m=0 -> lanes 0-15, reg 0) and
// the nonlinearity is in-wave: NO gh LDS round-trip. Double-buffered h A-tile
// -> ONE barrier/step, done as raw s_barrier with lgkmcnt-only drain so global
// loads stay in flight across steps. gi prefetched 2 steps ahead in registers.
__global__ __launch_bounds__(512, 2) void gru_mfma_kernel(
    const float* __restrict__ gi_f, const float* __restrict__ gi_b,
    const __hip_bfloat16* __restrict__ whhbf_f, const __hip_bfloat16* __restrict__ whhbf_b,
    const float* __restrict__ bhh_f, const float* __restrict__ bhh_b,
    float* __restrict__ sent_rep, __hip_bfloat16* __restrict__ sent_rep_bf,
    float* __restrict__ hT_f, float* __restrict__ hT_b) {
  __shared__ __hip_bfloat16 htile[2][16 * HPAD];  // row 0 real, rows 1-15 zero
  __shared__ float stg32[16][256];                // sent_rep staging ring
  __shared__ __hip_bfloat16 stgbf[16][256];
  const int blk = blockIdx.x;
  const int dir = blk >> 5, b = blk & 31;
  const int tid = threadIdx.x;
  const int lane = tid & 63, w = tid >> 6;
  const float* gi = dir ? gi_b : gi_f;
  const __hip_bfloat16* whh = dir ? whhbf_b : whhbf_f;
  const float* bhh = dir ? bhh_b : bhh_f;

  for (int i = tid; i < 16 * HPAD; i += 512) {
    htile[0][i] = __float2bfloat16(0.f);
    htile[1][i] = __float2bfloat16(0.f);
  }

  const int c = lane & 15;
  const int kq = (lane >> 4) * 8;
  const int d0 = w * 32 + c, d1 = d0 + 16;

  // one-time weight fragment load: bfrag[g*2+a] covers rows g*256 + w*32 + a*16 + [0,16)
  short8 bfrag[6][8];
#pragma unroll
  for (int g = 0; g < 3; ++g)
#pragma unroll
    for (int a = 0; a < 2; ++a)
#pragma unroll
      for (int kt = 0; kt < 8; ++kt)
        bfrag[g * 2 + a][kt] =
            *(const short8*)(whh + (size_t)(g * 256 + w * 32 + a * 16 + c) * 256 + kt * 32 + kq);

  float bh[3][2] = {{0.f, 0.f}, {0.f, 0.f}, {0.f, 0.f}};
  float hreg[2] = {0.f, 0.f};
  float gA[3][2], gB[3][2];
  if (lane < 16) {
#pragma unroll
    for (int g = 0; g < 3; ++g) {
      bh[g][0] = bhh[g * 256 + d0];
      bh[g][1] = bhh[g * 256 + d1];
    }
    const size_t r0 = (size_t)((b << 8) + (dir ? 255 : 0));
    const size_t r1 = (size_t)((b << 8) + (dir ? 254 : 1));
#pragma unroll
    for (int g = 0; g < 3; ++g) {
      gA[g][0] = gi[r0 * 768 + g * 256 + d0];
      gA[g][1] = gi[r0 * 768 + g * 256 + d1];
      gB[g][0] = gi[r1 * 768 + g * 256 + d0];
      gB[g][1] = gi[r1 * 768 + g * 256 + d1];
    }
  }
  asm volatile("s_waitcnt lgkmcnt(0)\n\ts_barrier" ::: "memory");

  auto body = [&](int t, float (&gc)[3][2]) {
    const __hip_bfloat16* hsrc = htile[t & 1];
    __hip_bfloat16* hdst = htile[(t + 1) & 1];
    f32x4 acc[6];
#pragma unroll
    for (int nt = 0; nt < 6; ++nt) acc[nt] = (f32x4){0.f, 0.f, 0.f, 0.f};
#pragma unroll
    for (int kt = 0; kt < 8; ++kt) {
      short8 av = *(const short8*)(&hsrc[c * HPAD + kt * 32 + kq]);
#pragma unroll
      for (int nt = 0; nt < 6; ++nt)
        acc[nt] = __builtin_amdgcn_mfma_f32_16x16x32_bf16(av, bfrag[nt][kt], acc[nt], 0, 0, 0);
    }
    if (lane < 16) {
#pragma unroll
      for (int a = 0; a < 2; ++a) {
        int d = a ? d1 : d0;
        float rr = fsigm(gc[0][a] + acc[a][0] + bh[0][a]);
        float zz = fsigm(gc[1][a] + acc[2 + a][0] + bh[1][a]);
        float nn = ftanh(gc[2][a] + rr * (acc[4 + a][0] + bh[2][a]));
        float hn = (1.f - zz) * nn + zz * hreg[a];
        hreg[a] = hn;
        hdst[d] = __float2bfloat16(hn);
        stg32[t & 15][d] = hn;
        stgbf[t & 15][d] = __float2bfloat16(hn);
      }
      if (t + 2 < Sd) {  // prefetch gi for t+2 (stays in flight across barriers)
        const size_t row2 = (size_t)((b << 8) + (dir ? (255 - (t + 2)) : (t + 2)));
#pragma unroll
        for (int g = 0; g < 3; ++g) {
          gc[g][0] = gi[row2 * 768 + g * 256 + d0];
          gc[g][1] = gi[row2 * 768 + g * 256 + d1];
        }
      }
    }
    asm volatile("s_waitcnt lgkmcnt(0)\n\ts_barrier" ::: "memory");
    if ((t & 7) == 7) {  // flush 8 staged steps; ring is 16 deep so no race
      const int base = t - 7;
#pragma unroll
      for (int i = 0; i < 4; ++i) {
        int idx = tid + i * 512;
        int u = idx >> 8, d = idx & 255;
        int st_ = base + u;
        int sg = dir ? (255 - st_) : st_;
        size_t rowg = (size_t)((b << 8) + sg);
        int col = dir ? (256 + d) : d;
        sent_rep[rowg * 512 + col] = stg32[st_ & 15][d];
        sent_rep_bf[rowg * 512 + col] = stgbf[st_ & 15][d];
      }
    }
  };

  for (int t = 0; t < Sd; t += 2) {
    body(t, gA);
    body(t + 1, gB);
  }
  if (lane < 16) {
    float* hT = dir ? hT_b : hT_f;
    hT[b * 256 + d0] = hreg[0];
    hT[b * 256 + d1] = hreg[1];
  }
}

// ---------------------------------------------------------------------------
// 5. doc_vec per torch view(B,2H) on stacked [2,B,H]. grid 32, block 512.
__global__ void docvec_kernel(const float* __restrict__ hTf, const float* __restrict__ hTb,
                              __hip_bfloat16* __restrict__ dv) {
  int b = blockIdx.x, jj = threadIdx.x;
  int idx = b * 512 + jj;
  int dsel = idx >> 13;            // /8192
  int rem = idx & 8191;
  int bp = rem >> 8, hp = rem & 255;
  float v = (dsel ? hTb : hTf)[bp * Hd + hp];
  dv[idx] = __float2bfloat16(v);
}

// 6. topic_mat via boundary differencing. grid 512 (b*16+t), block 256.
__global__ void topic_kernel(const int* __restrict__ tse, const float* __restrict__ sent_rep,
                             __hip_bfloat16* __restrict__ topic_bf) {
  int bt = blockIdx.x;
  int b = bt >> 4;
  int st = tse[bt * 2], en = tse[bt * 2 + 1];   // 1-indexed
  int dd = threadIdx.x;
  auto pad = [&](int i, int col) -> float {
    if (i < 1 || i > Sd) return 0.f;
    return sent_rep[((size_t)((b << 8) + (i - 1))) * 512 + col];
  };
  float fwd = pad(en, dd) - pad(st - 1, dd);
  float bwd = pad(st, Hd + dd) - pad(en + 1, Hd + dd);
  topic_bf[(size_t)bt * 512 + dd] = __float2bfloat16(fwd);
  topic_bf[(size_t)bt * 512 + Hd + dd] = __float2bfloat16(bwd);
}

// ---------------------------------------------------------------------------
// 7. attention scores. grid 8192 (b*256+s), block 256.
__global__ void scores_kernel(const float* __restrict__ P, const float* __restrict__ R,
                              const float* __restrict__ Q, const float* __restrict__ v_att,
                              const int* __restrict__ tse,
                              float* __restrict__ dsc, float* __restrict__ tsc) {
  int r = blockIdx.x;
  int b = r >> 8, s = r & 255;
  int tid = threadIdx.x;
  int tsel = Td - 1;
  for (int t = 0; t < Td; ++t) {
    if (tse[(b * Td + t) * 2 + 1] >= s + 1) { tsel = t; break; }
  }
  const float* q = Q + (size_t)r * 1024;
  const float* p = P + (size_t)b * 1024;
  const float* rr = R + (size_t)(b * Td + tsel) * 1024;
  float accd = 0.f, acct = 0.f;
  for (int n = tid; n < 1024; n += 256) {
    float qv = q[n];
    float vv = v_att[n];
    accd += ftanh(p[n] + qv) * vv;
    acct += ftanh(rr[n] + qv) * vv;
  }
  __shared__ float s1[256], s2[256];
  s1[tid] = accd; s2[tid] = acct;
  __syncthreads();
  for (int off = 128; off > 0; off >>= 1) {
    if (tid < off) { s1[tid] += s1[tid + off]; s2[tid] += s2[tid + off]; }
    __syncthreads();
  }
  if (tid == 0) { dsc[r] = s1[0]; tsc[r] = s2[0]; }
}

// 8. softmax over s per batch (both score sets). grid 32, block 256.
__global__ void softmax_kernel(const float* __restrict__ dsc, const float* __restrict__ tsc,
                               float* __restrict__ dw, float* __restrict__ tw) {
  int b = blockIdx.x, s = threadIdx.x;
  __shared__ float red[256];
  for (int which = 0; which < 2; ++which) {
    const float* src = which ? tsc : dsc;
    float v = src[b * Sd + s];
    red[s] = v; __syncthreads();
    for (int off = 128; off > 0; off >>= 1) {
      if (s < off) red[s] = fmaxf(red[s], red[s + off]);
      __syncthreads();
    }
    float m = red[0]; __syncthreads();
    float e = __expf(v - m);
    red[s] = e; __syncthreads();
    for (int off = 128; off > 0; off >>= 1) {
      if (s < off) red[s] += red[s + off];
      __syncthreads();
    }
    float sum = red[0]; __syncthreads();
    (which ? tw : dw)[b * Sd + s] = e / sum;
  }
}

// 9. final head. grid 8192, block 256. OUTPUT IS FP32.
__global__ void final_kernel(const float* __restrict__ U, const float* __restrict__ dvd,
                             const float* __restrict__ tvd, const float* __restrict__ dw,
                             const float* __restrict__ tw, const float* __restrict__ b_dna,
                             const float* __restrict__ w_out,
                             const float* __restrict__ b_out,
                             const int* __restrict__ tse, float* __restrict__ out) {
  int r = blockIdx.x;
  int b = r >> 8, s = r & 255;
  int dd = threadIdx.x;
  int tsel = Td - 1;
  for (int t = 0; t < Td; ++t) {
    if (tse[(b * Td + t) * 2 + 1] >= s + 1) { tsel = t; break; }
  }
  float wdv = dw[b * Sd + s], wtv = tw[b * Sd + s];
  float x = U[(size_t)r * Dd + dd] + wdv * dvd[b * Dd + dd] +
            wtv * tvd[(size_t)(b * Td + tsel) * Dd + dd] + b_dna[dd];
  x = fmaxf(x, 0.f);
  float term = x * w_out[dd];
  __shared__ float red[256];
  red[dd] = term; __syncthreads();
  for (int off = 128; off > 0; off >>= 1) {
    if (dd < off) red[dd] += red[dd + off];
    __syncthreads();
  }
  if (dd == 0) out[r] = red[0] + b_out[0];
}

// ---------------------------------------------------------------------------
static void launch_gemm(const __hip_bfloat16* A, int lda, const __hip_bfloat16* W, int ldw,
                        float* C, int ldc, int M, int N, int K,
                        const float* bias, hipStream_t stream) {
  dim3 grid((M + 63) / 64, N / 64);
  gemm_xwt_kernel<<<grid, 256, 0, stream>>>(A, lda, W, ldw, C, ldc, M, N, K, bias);
}

extern "C" void kernel_launch(void* const* d_in, const int* in_sizes, int n_in,
                              void* d_out, int out_size, void* d_ws, size_t ws_size,
                              hipStream_t stream) {
  const int* word_ids = (const int*)d_in[0];
  const int* tse      = (const int*)d_in[1];
  const float* emb   = (const float*)d_in[2];
  const float* wih_f = (const float*)d_in[3];
  const float* whh_f = (const float*)d_in[4];
  const float* bih_f = (const float*)d_in[5];
  const float* bhh_f = (const float*)d_in[6];
  const float* wih_b = (const float*)d_in[7];
  const float* whh_b = (const float*)d_in[8];
  const float* bih_b = (const float*)d_in[9];
  const float* bhh_b = (const float*)d_in[10];
  const float* w_att = (const float*)d_in[11];
  const float* v_att = (const float*)d_in[12];
  const float* w_dna = (const float*)d_in[13];
  const float* b_dna = (const float*)d_in[14];
  const float* w_out = (const float*)d_in[15];
  const float* b_out = (const float*)d_in[16];
  float* out = (float*)d_out;
  char* ws = (char*)d_ws;

  const int M = Bd * Sd;  // 8192

  // workspace layout (bytes)
  size_t off = 0;
  auto alloc = [&](size_t sz) { size_t o = off; off += (sz + 255) & ~(size_t)255; return o; };
  size_t o_svbf   = alloc((size_t)M * EP * 2);          // A_pad bf16 [8192,320]
  size_t o_wpadf  = alloc((size_t)768 * EP * 2);
  size_t o_wpadb  = alloc((size_t)768 * EP * 2);
  size_t o_whhbf  = alloc((size_t)768 * Hd * 2 * 2);    // whh f+b bf16
  size_t o_wattT  = alloc((size_t)1024 * 1024 * 2);     // WattT[n][k] bf16
  size_t o_wdnaT  = alloc((size_t)Dd * 1024 * 2);       // WdnaT[n][k] bf16
  size_t o_hTf    = alloc((size_t)Bd * Hd * 4);
  size_t o_hTb    = alloc((size_t)Bd * Hd * 4);
  size_t o_dvbf   = alloc((size_t)Bd * 512 * 2);        // doc_vec bf16
  size_t o_topbf  = alloc((size_t)Bd * Td * 512 * 2);   // topic_mat bf16
  size_t o_P      = alloc((size_t)Bd * 1024 * 4);
  size_t o_R      = alloc((size_t)Bd * Td * 1024 * 4);
  size_t o_dvd    = alloc((size_t)Bd * Dd * 4);
  size_t o_tvd    = alloc((size_t)Bd * Td * Dd * 4);
  size_t o_dsc    = alloc((size_t)Bd * Sd * 4);
  size_t o_tsc    = alloc((size_t)Bd * Sd * 4);
  size_t o_dw     = alloc((size_t)Bd * Sd * 4);
  size_t o_tw     = alloc((size_t)Bd * Sd * 4);
  size_t o_srep32 = alloc((size_t)M * 512 * 4);         // sent_rep fp32
  size_t o_srepbf = alloc((size_t)M * 512 * 2);         // sent_rep bf16
  size_t o_gif    = alloc((size_t)M * 768 * 4);         // gi fwd fp32
  size_t o_gib    = alloc((size_t)M * 768 * 4);         // gi bwd fp32
  // Q [8192,1024] f32 and U [8192,256] f32 overlay the dead gi region after GRU
  size_t o_Q = o_gif;
  size_t o_U = o_gif + (size_t)M * 1024 * 4;
  (void)ws_size;

  __hip_bfloat16* svbf   = (__hip_bfloat16*)(ws + o_svbf);
  __hip_bfloat16* wpadf  = (__hip_bfloat16*)(ws + o_wpadf);
  __hip_bfloat16* wpadb  = (__hip_bfloat16*)(ws + o_wpadb);
  __hip_bfloat16* whhbf_f = (__hip_bfloat16*)(ws + o_whhbf);
  __hip_bfloat16* whhbf_b = whhbf_f + 768 * Hd;
  __hip_bfloat16* wattT  = (__hip_bfloat16*)(ws + o_wattT);
  __hip_bfloat16* wdnaT  = (__hip_bfloat16*)(ws + o_wdnaT);
  float* hTf = (float*)(ws + o_hTf);
  float* hTb = (float*)(ws + o_hTb);
  __hip_bfloat16* dvbf  = (__hip_bfloat16*)(ws + o_dvbf);
  __hip_bfloat16* topbf = (__hip_bfloat16*)(ws + o_topbf);
  float* P   = (float*)(ws + o_P);
  float* R   = (float*)(ws + o_R);
  float* dvd = (float*)(ws + o_dvd);
  float* tvd = (float*)(ws + o_tvd);
  float* dsc = (float*)(ws + o_dsc);
  float* tsc = (float*)(ws + o_tsc);
  float* dw  = (float*)(ws + o_dw);
  float* tw  = (float*)(ws + o_tw);
  float* srep32 = (float*)(ws + o_srep32);
  __hip_bfloat16* srepbf = (__hip_bfloat16*)(ws + o_srepbf);
  float* gif = (float*)(ws + o_gif);
  float* gib = (float*)(ws + o_gib);
  float* Q = (float*)(ws + o_Q);
  float* U = (float*)(ws + o_U);

  // 1. sentence means -> padded bf16 activations
  sent_means_kernel<<<M, EP, 0, stream>>>(word_ids, emb, svbf);
  // 2. weight prep (fp32 -> bf16)
  pad_wih_kernel<<<(768 * EP) / 256, 256, 0, stream>>>(wih_f, wpadf);
  pad_wih_kernel<<<(768 * EP) / 256, 256, 0, stream>>>(wih_b, wpadb);
  f2bf_kernel<<<(768 * Hd) / 256, 256, 0, stream>>>(whh_f, whhbf_f, 768 * Hd);
  f2bf_kernel<<<(768 * Hd) / 256, 256, 0, stream>>>(whh_b, whhbf_b, 768 * Hd);
  transpose_att_kernel<<<(1024 * 1024) / 256, 256, 0, stream>>>(w_att, wattT);
  transpose_dna_kernel<<<(Dd * 1024) / 256, 256, 0, stream>>>(w_dna, wdnaT);
  // 3. input projections gi = sv @ Wih^T + bih
  launch_gemm(svbf, EP, wpadf, EP, gif, 768, M, 768, EP, bih_f, stream);
  launch_gemm(svbf, EP, wpadb, EP, gib, 768, M, 768, EP, bih_b, stream);
  // 4. bidirectional GRU recurrence (persistent-weight MFMA v3)
  gru_mfma_kernel<<<64, 512, 0, stream>>>(gif, gib, whhbf_f, whhbf_b, bhh_f, bhh_b,
                                          srep32, srepbf, hTf, hTb);
  // 5/6. doc_vec + topic_mat
  docvec_kernel<<<Bd, 512, 0, stream>>>(hTf, hTb, dvbf);
  topic_kernel<<<Bd * Td, 256, 0, stream>>>(tse, srep32, topbf);
  // 7. attention/dense GEMMs
  launch_gemm(srepbf, 512, wattT + 512, 1024, Q, 1024, M, 1024, 512, nullptr, stream);
  launch_gemm(dvbf, 512, wattT, 1024, P, 1024, Bd, 1024, 512, nullptr, stream);
  launch_gemm(topbf, 512, wattT, 1024, R, 1024, Bd * Td, 1024, 512, nullptr, stream);
  launch_gemm(srepbf, 512, wdnaT, 1024, U, Dd, M, Dd, 512, nullptr, stream);
  launch_gemm(dvbf, 512, wdnaT + 512, 1024, dvd, Dd, Bd, Dd, 512, nullptr, stream);
  launch_gemm(topbf, 512, wdnaT + 512, 1024, tvd, Dd, Bd * Td, Dd, 512, nullptr, stream);
  // 8. scores + softmax
  scores_kernel<<<M, 256, 0, stream>>>(P, R, Q, v_att, tse, dsc, tsc);
  softmax_kernel<<<Bd, 256, 0, stream>>>(dsc, tsc, dw, tw);
  // 9. fused dense head -> logits (fp32)
  final_kernel<<<M, 256, 0, stream>>>(U, dvd, tvd, dw, tw, b_dna, w_out, b_out, tse, out);
}

// Round 8
// 623.295 us; speedup vs baseline: 1.5470x; 1.5470x over previous
//
#include <hip/hip_runtime.h>
#include <hip/hip_bf16.h>
#include <math.h>

// Dims (fixed by the problem)
#define Bd 32
#define Sd 256
#define Ld 24
#define Ed 300
#define Hd 256
#define Td 16
#define Dd 256
#define EP 320    // E padded to multiple of 32

using short8 = __attribute__((ext_vector_type(8))) short;
using f32x4  = __attribute__((ext_vector_type(4))) float;

// fast transcendentals (v_exp_f32 path; saturate correctly at +-inf)
__device__ __forceinline__ float fsigm(float x) { return 1.f / (1.f + __expf(-x)); }
__device__ __forceinline__ float ftanh(float x) {
  float e = __expf(2.f * x);
  return 1.f - 2.f / (e + 1.f);
}

// ---------------------------------------------------------------------------
// 1. sentence means: A_pad[r][k] = bf16(mean_w emb[word_ids[r][w]][k]), k<300, else 0
// grid 8192, block 320. emb is FLOAT32.
__global__ void sent_means_kernel(const int* __restrict__ wids,
                                  const float* __restrict__ emb,
                                  __hip_bfloat16* __restrict__ apad) {
  int r = blockIdx.x;
  __shared__ int ids[Ld];
  int tid = threadIdx.x;
  if (tid < Ld) ids[tid] = wids[r * Ld + tid];
  __syncthreads();
  float acc = 0.f;
  if (tid < Ed) {
#pragma unroll
    for (int w = 0; w < Ld; ++w) acc += emb[(size_t)ids[w] * Ed + tid];
    acc *= (1.f / 24.f);
  }
  apad[r * EP + tid] = __float2bfloat16(tid < Ed ? acc : 0.f);
}

// ---------------------------------------------------------------------------
// 2. weight prep (all sources FLOAT32 -> bf16 for MFMA)
__global__ void pad_wih_kernel(const float* __restrict__ src,
                               __hip_bfloat16* __restrict__ dst) {
  int i = blockIdx.x * 256 + threadIdx.x;   // 768*320
  if (i >= 768 * EP) return;
  int n = i / EP, k = i % EP;
  dst[i] = __float2bfloat16(k < Ed ? src[n * Ed + k] : 0.f);
}
__global__ void f2bf_kernel(const float* __restrict__ src,
                            __hip_bfloat16* __restrict__ dst, int n) {
  int i = blockIdx.x * 256 + threadIdx.x;
  if (i < n) dst[i] = __float2bfloat16(src[i]);
}
__global__ void transpose_att_kernel(const float* __restrict__ src,
                                     __hip_bfloat16* __restrict__ dst) {
  int i = blockIdx.x * 256 + threadIdx.x;   // 1024*1024: dst[n][k] = src[k][n]
  int n = i >> 10, k = i & 1023;
  dst[i] = __float2bfloat16(src[k * 1024 + n]);
}
__global__ void transpose_dna_kernel(const float* __restrict__ src,
                                     __hip_bfloat16* __restrict__ dst) {
  int i = blockIdx.x * 256 + threadIdx.x;   // 256*1024: dst[n][k] = src[k][n]
  int n = i >> 10, k = i & 1023;
  dst[i] = __float2bfloat16(src[k * Dd + n]);
}

// ---------------------------------------------------------------------------
// 3. MFMA GEMM: C[M,N] = A[M,K] @ W[N,K]^T (+bias[n]); A,W bf16 row-major, C fp32.
__global__ __launch_bounds__(256) void gemm_xwt_kernel(
    const __hip_bfloat16* __restrict__ A, int lda,
    const __hip_bfloat16* __restrict__ W, int ldw,
    float* __restrict__ C, int ldc,
    int M, int N, int K,
    const float* __restrict__ bias) {
  __shared__ unsigned short la[64][32];
  __shared__ unsigned short lb[64][32];
  const int tid = threadIdx.x;
  const int m0 = blockIdx.x * 64, n0 = blockIdx.y * 64;
  const int lane = tid & 63, wid = tid >> 6;
  const int wm = (wid >> 1) * 32, wn = (wid & 1) * 32;
  const int lrow = tid >> 2, lcol = (tid & 3) * 8;
  f32x4 acc00 = {0.f, 0.f, 0.f, 0.f}, acc01 = {0.f, 0.f, 0.f, 0.f};
  f32x4 acc10 = {0.f, 0.f, 0.f, 0.f}, acc11 = {0.f, 0.f, 0.f, 0.f};
  int arow = m0 + lrow; if (arow > M - 1) arow = M - 1;
  const int brow = n0 + lrow;
  const int fr = lane & 15, fq = (lane >> 4) * 8;
  for (int k0 = 0; k0 < K; k0 += 32) {
    uint4 av = *(const uint4*)(A + (size_t)arow * lda + k0 + lcol);
    uint4 bv = *(const uint4*)(W + (size_t)brow * ldw + k0 + lcol);
    *(uint4*)(&la[lrow][lcol]) = av;
    *(uint4*)(&lb[lrow][lcol]) = bv;
    __syncthreads();
    short8 a0 = *(const short8*)(&la[wm + fr][fq]);
    short8 a1 = *(const short8*)(&la[wm + 16 + fr][fq]);
    short8 b0 = *(const short8*)(&lb[wn + fr][fq]);
    short8 b1 = *(const short8*)(&lb[wn + 16 + fr][fq]);
    acc00 = __builtin_amdgcn_mfma_f32_16x16x32_bf16(a0, b0, acc00, 0, 0, 0);
    acc01 = __builtin_amdgcn_mfma_f32_16x16x32_bf16(a0, b1, acc01, 0, 0, 0);
    acc10 = __builtin_amdgcn_mfma_f32_16x16x32_bf16(a1, b0, acc10, 0, 0, 0);
    acc11 = __builtin_amdgcn_mfma_f32_16x16x32_bf16(a1, b1, acc11, 0, 0, 0);
    __syncthreads();
  }
  const int rq = (lane >> 4) * 4;
  f32x4 accs[2][2] = {{acc00, acc01}, {acc10, acc11}};
  for (int i = 0; i < 2; ++i)
    for (int j = 0; j < 2; ++j) {
      int n = n0 + wn + j * 16 + fr;
      float bv = bias ? bias[n] : 0.f;
      for (int r2 = 0; r2 < 4; ++r2) {
        int m = m0 + wm + i * 16 + rq + r2;
        if (m < M) C[(size_t)m * ldc + n] = accs[i][j][r2] + bv;
      }
    }
}

// ---------------------------------------------------------------------------
// 4. Persistent-weight MFMA GRU (v2 skeleton + LDS-staged gi + broadcast h-row).
// grid 64 (dir=blk>>5, b=blk&31), block 512.
// - Whh as register B-fragments (wave w owns gate rows [96w,96w+96)), as in r5/r6.
// - gi staged through LDS in 8-step chunks, double-buffered, burst-loaded 8
//   steps ahead (3 float4/thread) -> no per-step HBM latency inside the
//   barrier-drained critical path.
// - h kept as ONE 256-elem bf16 row read by broadcast (all lanes same addr,
//   conflict-free); A-fragment rows m>0 are zeroed by cndmask instead of a
//   16-row zero tile.
__global__ __launch_bounds__(512, 2) void gru_mfma_kernel(
    const float* __restrict__ gi_f, const float* __restrict__ gi_b,
    const __hip_bfloat16* __restrict__ whhbf_f, const __hip_bfloat16* __restrict__ whhbf_b,
    const float* __restrict__ bhh_f, const float* __restrict__ bhh_b,
    float* __restrict__ sent_rep, __hip_bfloat16* __restrict__ sent_rep_bf,
    float* __restrict__ hT_f, float* __restrict__ hT_b) {
  __shared__ float gi_lds[2][8][768];          // 49152 B
  __shared__ __hip_bfloat16 h_bf[256];         // 512 B (single live h row)
  __shared__ float gh[768];                    // 3072 B
  __shared__ float stg32[8][256];              // 8192 B  -> total ~60.9 KB
  const int blk = blockIdx.x;
  const int dir = blk >> 5, b = blk & 31;
  const int tid = threadIdx.x;
  const int lane = tid & 63, w = tid >> 6;
  const float* gi = dir ? gi_b : gi_f;
  const __hip_bfloat16* whh = dir ? whhbf_b : whhbf_f;
  const float* bhh = dir ? bhh_b : bhh_f;

  if (tid < 256) h_bf[tid] = __float2bfloat16(0.f);

  // one-time weight fragment load (identical mapping to r5/r6 verified kernel)
  short8 bfrag[6][8];
  {
    const int n0 = w * 96 + (lane & 15);
    const int kq = (lane >> 4) * 8;
#pragma unroll
    for (int nt = 0; nt < 6; ++nt)
#pragma unroll
      for (int kt = 0; kt < 8; ++kt)
        bfrag[nt][kt] = *(const short8*)(whh + (size_t)(n0 + nt * 16) * 256 + kt * 32 + kq);
  }
  float bhr = 0.f, bhz = 0.f, bhn = 0.f, hprev = 0.f;
  if (tid < 256) { bhr = bhh[tid]; bhz = bhh[256 + tid]; bhn = bhh[512 + tid]; }

  // burst-load one 8-step gi chunk into gi_lds[buf] (all 512 threads)
  auto burst = [&](int tstart, int buf) {
#pragma unroll
    for (int i = 0; i < 3; ++i) {
      int idx = tid + i * 512;               // 0..1535 = 8 rows x 192 float4
      int u = idx / 192;
      int c4 = (idx - u * 192) * 4;
      int s = dir ? (255 - (tstart + u)) : (tstart + u);
      float4 v = *(const float4*)(gi + (size_t)(((b << 8) + s) * 768 + c4));
      *(float4*)(&gi_lds[buf][u][c4]) = v;
    }
  };
  burst(0, 0);
  __syncthreads();

  const int c = lane & 15;
  const int kq = (lane >> 4) * 8;
  const short8 zero8 = {0, 0, 0, 0, 0, 0, 0, 0};

  for (int t = 0; t < Sd; ++t) {
    if ((t & 7) == 0 && t + 8 < Sd) burst(t + 8, ((t >> 3) + 1) & 1);
    // MFMA phase: broadcast-read h row, mask rows m>0 to zero
    f32x4 acc[6];
#pragma unroll
    for (int nt = 0; nt < 6; ++nt) acc[nt] = (f32x4){0.f, 0.f, 0.f, 0.f};
#pragma unroll
    for (int kt = 0; kt < 8; ++kt) {
      short8 av = *(const short8*)(&h_bf[kt * 32 + kq]);
      if (c != 0) av = zero8;
#pragma unroll
      for (int nt = 0; nt < 6; ++nt)
        acc[nt] = __builtin_amdgcn_mfma_f32_16x16x32_bf16(av, bfrag[nt][kt], acc[nt], 0, 0, 0);
    }
    if (lane < 16) {
#pragma unroll
      for (int nt = 0; nt < 6; ++nt)
        gh[w * 96 + nt * 16 + lane] = acc[nt][0];
    }
    __syncthreads();
    // gate phase (gi from LDS, stride-1)
    if (tid < 256) {
      const float* gl = gi_lds[(t >> 3) & 1][t & 7];
      float rr = fsigm(gl[tid] + gh[tid] + bhr);
      float zz = fsigm(gl[256 + tid] + gh[256 + tid] + bhz);
      float nn = ftanh(gl[512 + tid] + rr * (gh[512 + tid] + bhn));
      float hn = (1.f - zz) * nn + zz * hprev;
      hprev = hn;
      h_bf[tid] = __float2bfloat16(hn);
      stg32[t & 7][tid] = hn;
    }
    __syncthreads();
    if ((t & 7) == 7) {  // flush 8 staged steps (stores drain at later barriers)
      const int base = t - 7;
#pragma unroll
      for (int i = 0; i < 4; ++i) {
        int idx = tid + i * 512;
        int u = idx >> 8, d = idx & 255;
        int sg = dir ? (255 - (base + u)) : (base + u);
        size_t rowg = (size_t)((b << 8) + sg);
        int col = dir ? (256 + d) : d;
        float v = stg32[u][d];
        sent_rep[rowg * 512 + col] = v;
        sent_rep_bf[rowg * 512 + col] = __float2bfloat16(v);
      }
    }
  }
  if (tid < 256) (dir ? hT_b : hT_f)[b * 256 + tid] = hprev;
}

// ---------------------------------------------------------------------------
// 5. doc_vec per torch view(B,2H) on stacked [2,B,H]. grid 32, block 512.
__global__ void docvec_kernel(const float* __restrict__ hTf, const float* __restrict__ hTb,
                              __hip_bfloat16* __restrict__ dv) {
  int b = blockIdx.x, jj = threadIdx.x;
  int idx = b * 512 + jj;
  int dsel = idx >> 13;            // /8192
  int rem = idx & 8191;
  int bp = rem >> 8, hp = rem & 255;
  float v = (dsel ? hTb : hTf)[bp * Hd + hp];
  dv[idx] = __float2bfloat16(v);
}

// 6. topic_mat via boundary differencing. grid 512 (b*16+t), block 256.
__global__ void topic_kernel(const int* __restrict__ tse, const float* __restrict__ sent_rep,
                             __hip_bfloat16* __restrict__ topic_bf) {
  int bt = blockIdx.x;
  int b = bt >> 4;
  int st = tse[bt * 2], en = tse[bt * 2 + 1];   // 1-indexed
  int dd = threadIdx.x;
  auto pad = [&](int i, int col) -> float {
    if (i < 1 || i > Sd) return 0.f;
    return sent_rep[((size_t)((b << 8) + (i - 1))) * 512 + col];
  };
  float fwd = pad(en, dd) - pad(st - 1, dd);
  float bwd = pad(st, Hd + dd) - pad(en + 1, Hd + dd);
  topic_bf[(size_t)bt * 512 + dd] = __float2bfloat16(fwd);
  topic_bf[(size_t)bt * 512 + Hd + dd] = __float2bfloat16(bwd);
}

// ---------------------------------------------------------------------------
// 7. attention scores. grid 8192 (b*256+s), block 256.
__global__ void scores_kernel(const float* __restrict__ P, const float* __restrict__ R,
                              const float* __restrict__ Q, const float* __restrict__ v_att,
                              const int* __restrict__ tse,
                              float* __restrict__ dsc, float* __restrict__ tsc) {
  int r = blockIdx.x;
  int b = r >> 8, s = r & 255;
  int tid = threadIdx.x;
  int tsel = Td - 1;
  for (int t = 0; t < Td; ++t) {
    if (tse[(b * Td + t) * 2 + 1] >= s + 1) { tsel = t; break; }
  }
  const float* q = Q + (size_t)r * 1024;
  const float* p = P + (size_t)b * 1024;
  const float* rr = R + (size_t)(b * Td + tsel) * 1024;
  float accd = 0.f, acct = 0.f;
  for (int n = tid; n < 1024; n += 256) {
    float qv = q[n];
    float vv = v_att[n];
    accd += ftanh(p[n] + qv) * vv;
    acct += ftanh(rr[n] + qv) * vv;
  }
  __shared__ float s1[256], s2[256];
  s1[tid] = accd; s2[tid] = acct;
  __syncthreads();
  for (int off = 128; off > 0; off >>= 1) {
    if (tid < off) { s1[tid] += s1[tid + off]; s2[tid] += s2[tid + off]; }
    __syncthreads();
  }
  if (tid == 0) { dsc[r] = s1[0]; tsc[r] = s2[0]; }
}

// 8. softmax over s per batch (both score sets). grid 32, block 256.
__global__ void softmax_kernel(const float* __restrict__ dsc, const float* __restrict__ tsc,
                               float* __restrict__ dw, float* __restrict__ tw) {
  int b = blockIdx.x, s = threadIdx.x;
  __shared__ float red[256];
  for (int which = 0; which < 2; ++which) {
    const float* src = which ? tsc : dsc;
    float v = src[b * Sd + s];
    red[s] = v; __syncthreads();
    for (int off = 128; off > 0; off >>= 1) {
      if (s < off) red[s] = fmaxf(red[s], red[s + off]);
      __syncthreads();
    }
    float m = red[0]; __syncthreads();
    float e = __expf(v - m);
    red[s] = e; __syncthreads();
    for (int off = 128; off > 0; off >>= 1) {
      if (s < off) red[s] += red[s + off];
      __syncthreads();
    }
    float sum = red[0]; __syncthreads();
    (which ? tw : dw)[b * Sd + s] = e / sum;
  }
}

// 9. final head. grid 8192, block 256. OUTPUT IS FP32.
__global__ void final_kernel(const float* __restrict__ U, const float* __restrict__ dvd,
                             const float* __restrict__ tvd, const float* __restrict__ dw,
                             const float* __restrict__ tw, const float* __restrict__ b_dna,
                             const float* __restrict__ w_out,
                             const float* __restrict__ b_out,
                             const int* __restrict__ tse, float* __restrict__ out) {
  int r = blockIdx.x;
  int b = r >> 8, s = r & 255;
  int dd = threadIdx.x;
  int tsel = Td - 1;
  for (int t = 0; t < Td; ++t) {
    if (tse[(b * Td + t) * 2 + 1] >= s + 1) { tsel = t; break; }
  }
  float wdv = dw[b * Sd + s], wtv = tw[b * Sd + s];
  float x = U[(size_t)r * Dd + dd] + wdv * dvd[b * Dd + dd] +
            wtv * tvd[(size_t)(b * Td + tsel) * Dd + dd] + b_dna[dd];
  x = fmaxf(x, 0.f);
  float term = x * w_out[dd];
  __shared__ float red[256];
  red[dd] = term; __syncthreads();
  for (int off = 128; off > 0; off >>= 1) {
    if (dd < off) red[dd] += red[dd + off];
    __syncthreads();
  }
  if (dd == 0) out[r] = red[0] + b_out[0];
}

// ---------------------------------------------------------------------------
static void launch_gemm(const __hip_bfloat16* A, int lda, const __hip_bfloat16* W, int ldw,
                        float* C, int ldc, int M, int N, int K,
                        const float* bias, hipStream_t stream) {
  dim3 grid((M + 63) / 64, N / 64);
  gemm_xwt_kernel<<<grid, 256, 0, stream>>>(A, lda, W, ldw, C, ldc, M, N, K, bias);
}

extern "C" void kernel_launch(void* const* d_in, const int* in_sizes, int n_in,
                              void* d_out, int out_size, void* d_ws, size_t ws_size,
                              hipStream_t stream) {
  const int* word_ids = (const int*)d_in[0];
  const int* tse      = (const int*)d_in[1];
  const float* emb   = (const float*)d_in[2];
  const float* wih_f = (const float*)d_in[3];
  const float* whh_f = (const float*)d_in[4];
  const float* bih_f = (const float*)d_in[5];
  const float* bhh_f = (const float*)d_in[6];
  const float* wih_b = (const float*)d_in[7];
  const float* whh_b = (const float*)d_in[8];
  const float* bih_b = (const float*)d_in[9];
  const float* bhh_b = (const float*)d_in[10];
  const float* w_att = (const float*)d_in[11];
  const float* v_att = (const float*)d_in[12];
  const float* w_dna = (const float*)d_in[13];
  const float* b_dna = (const float*)d_in[14];
  const float* w_out = (const float*)d_in[15];
  const float* b_out = (const float*)d_in[16];
  float* out = (float*)d_out;
  char* ws = (char*)d_ws;

  const int M = Bd * Sd;  // 8192

  // workspace layout (bytes)
  size_t off = 0;
  auto alloc = [&](size_t sz) { size_t o = off; off += (sz + 255) & ~(size_t)255; return o; };
  size_t o_svbf   = alloc((size_t)M * EP * 2);          // A_pad bf16 [8192,320]
  size_t o_wpadf  = alloc((size_t)768 * EP * 2);
  size_t o_wpadb  = alloc((size_t)768 * EP * 2);
  size_t o_whhbf  = alloc((size_t)768 * Hd * 2 * 2);    // whh f+b bf16
  size_t o_wattT  = alloc((size_t)1024 * 1024 * 2);     // WattT[n][k] bf16
  size_t o_wdnaT  = alloc((size_t)Dd * 1024 * 2);       // WdnaT[n][k] bf16
  size_t o_hTf    = alloc((size_t)Bd * Hd * 4);
  size_t o_hTb    = alloc((size_t)Bd * Hd * 4);
  size_t o_dvbf   = alloc((size_t)Bd * 512 * 2);        // doc_vec bf16
  size_t o_topbf  = alloc((size_t)Bd * Td * 512 * 2);   // topic_mat bf16
  size_t o_P      = alloc((size_t)Bd * 1024 * 4);
  size_t o_R      = alloc((size_t)Bd * Td * 1024 * 4);
  size_t o_dvd    = alloc((size_t)Bd * Dd * 4);
  size_t o_tvd    = alloc((size_t)Bd * Td * Dd * 4);
  size_t o_dsc    = alloc((size_t)Bd * Sd * 4);
  size_t o_tsc    = alloc((size_t)Bd * Sd * 4);
  size_t o_dw     = alloc((size_t)Bd * Sd * 4);
  size_t o_tw     = alloc((size_t)Bd * Sd * 4);
  size_t o_srep32 = alloc((size_t)M * 512 * 4);         // sent_rep fp32
  size_t o_srepbf = alloc((size_t)M * 512 * 2);         // sent_rep bf16
  size_t o_gif    = alloc((size_t)M * 768 * 4);         // gi fwd fp32
  size_t o_gib    = alloc((size_t)M * 768 * 4);         // gi bwd fp32
  // Q [8192,1024] f32 and U [8192,256] f32 overlay the dead gi region after GRU
  size_t o_Q = o_gif;
  size_t o_U = o_gif + (size_t)M * 1024 * 4;
  (void)ws_size;

  __hip_bfloat16* svbf   = (__hip_bfloat16*)(ws + o_svbf);
  __hip_bfloat16* wpadf  = (__hip_bfloat16*)(ws + o_wpadf);
  __hip_bfloat16* wpadb  = (__hip_bfloat16*)(ws + o_wpadb);
  __hip_bfloat16* whhbf_f = (__hip_bfloat16*)(ws + o_whhbf);
  __hip_bfloat16* whhbf_b = whhbf_f + 768 * Hd;
  __hip_bfloat16* wattT  = (__hip_bfloat16*)(ws + o_wattT);
  __hip_bfloat16* wdnaT  = (__hip_bfloat16*)(ws + o_wdnaT);
  float* hTf = (float*)(ws + o_hTf);
  float* hTb = (float*)(ws + o_hTb);
  __hip_bfloat16* dvbf  = (__hip_bfloat16*)(ws + o_dvbf);
  __hip_bfloat16* topbf = (__hip_bfloat16*)(ws + o_topbf);
  float* P   = (float*)(ws + o_P);
  float* R   = (float*)(ws + o_R);
  float* dvd = (float*)(ws + o_dvd);
  float* tvd = (float*)(ws + o_tvd);
  float* dsc = (float*)(ws + o_dsc);
  float* tsc = (float*)(ws + o_tsc);
  float* dw  = (float*)(ws + o_dw);
  float* tw  = (float*)(ws + o_tw);
  float* srep32 = (float*)(ws + o_srep32);
  __hip_bfloat16* srepbf = (__hip_bfloat16*)(ws + o_srepbf);
  float* gif = (float*)(ws + o_gif);
  float* gib = (float*)(ws + o_gib);
  float* Q = (float*)(ws + o_Q);
  float* U = (float*)(ws + o_U);

  // 1. sentence means -> padded bf16 activations
  sent_means_kernel<<<M, EP, 0, stream>>>(word_ids, emb, svbf);
  // 2. weight prep (fp32 -> bf16)
  pad_wih_kernel<<<(768 * EP) / 256, 256, 0, stream>>>(wih_f, wpadf);
  pad_wih_kernel<<<(768 * EP) / 256, 256, 0, stream>>>(wih_b, wpadb);
  f2bf_kernel<<<(768 * Hd) / 256, 256, 0, stream>>>(whh_f, whhbf_f, 768 * Hd);
  f2bf_kernel<<<(768 * Hd) / 256, 256, 0, stream>>>(whh_b, whhbf_b, 768 * Hd);
  transpose_att_kernel<<<(1024 * 1024) / 256, 256, 0, stream>>>(w_att, wattT);
  transpose_dna_kernel<<<(Dd * 1024) / 256, 256, 0, stream>>>(w_dna, wdnaT);
  // 3. input projections gi = sv @ Wih^T + bih
  launch_gemm(svbf, EP, wpadf, EP, gif, 768, M, 768, EP, bih_f, stream);
  launch_gemm(svbf, EP, wpadb, EP, gib, 768, M, 768, EP, bih_b, stream);
  // 4. bidirectional GRU recurrence (persistent-weight MFMA, LDS-staged gi)
  gru_mfma_kernel<<<64, 512, 0, stream>>>(gif, gib, whhbf_f, whhbf_b, bhh_f, bhh_b,
                                          srep32, srepbf, hTf, hTb);
  // 5/6. doc_vec + topic_mat
  docvec_kernel<<<Bd, 512, 0, stream>>>(hTf, hTb, dvbf);
  topic_kernel<<<Bd * Td, 256, 0, stream>>>(tse, srep32, topbf);
  // 7. attention/dense GEMMs
  launch_gemm(srepbf, 512, wattT + 512, 1024, Q, 1024, M, 1024, 512, nullptr, stream);
  launch_gemm(dvbf, 512, wattT, 1024, P, 1024, Bd, 1024, 512, nullptr, stream);
  launch_gemm(topbf, 512, wattT, 1024, R, 1024, Bd * Td, 1024, 512, nullptr, stream);
  launch_gemm(srepbf, 512, wdnaT, 1024, U, Dd, M, Dd, 512, nullptr, stream);
  launch_gemm(dvbf, 512, wdnaT + 512, 1024, dvd, Dd, Bd, Dd, 512, nullptr, stream);
  launch_gemm(topbf, 512, wdnaT + 512, 1024, tvd, Dd, Bd * Td, Dd, 512, nullptr, stream);
  // 8. scores + softmax
  scores_kernel<<<M, 256, 0, stream>>>(P, R, Q, v_att, tse, dsc, tsc);
  softmax_kernel<<<Bd, 256, 0, stream>>>(dsc, tsc, dw, tw);
  // 9. fused dense head -> logits (fp32)
  final_kernel<<<M, 256, 0, stream>>>(U, dvd, tvd, dw, tw, b_dna, w_out, b_out, tse, out);
}

// Round 9
// 582.032 us; speedup vs baseline: 1.6567x; 1.0709x over previous
//
#include <hip/hip_runtime.h>
#include <hip/hip_bf16.h>
#include <math.h>

// Dims (fixed by the problem)
#define Bd 32
#define Sd 256
#define Ld 24
#define Ed 300
#define Hd 256
#define Td 16
#define Dd 256
#define EP 320    // E padded to multiple of 32

using short8 = __attribute__((ext_vector_type(8))) short;
using f32x4  = __attribute__((ext_vector_type(4))) float;

// fast transcendentals (v_exp_f32 path; saturate correctly at +-inf)
__device__ __forceinline__ float fsigm(float x) { return 1.f / (1.f + __expf(-x)); }
__device__ __forceinline__ float ftanh(float x) {
  float e = __expf(2.f * x);
  return 1.f - 2.f / (e + 1.f);
}

// ---------------------------------------------------------------------------
// 1. sentence means: A_pad[r][k] = bf16(mean_w emb[word_ids[r][w]][k]), k<300, else 0
// grid 8192, block 320. emb is FLOAT32.
__global__ void sent_means_kernel(const int* __restrict__ wids,
                                  const float* __restrict__ emb,
                                  __hip_bfloat16* __restrict__ apad) {
  int r = blockIdx.x;
  __shared__ int ids[Ld];
  int tid = threadIdx.x;
  if (tid < Ld) ids[tid] = wids[r * Ld + tid];
  __syncthreads();
  float acc = 0.f;
  if (tid < Ed) {
#pragma unroll
    for (int w = 0; w < Ld; ++w) acc += emb[(size_t)ids[w] * Ed + tid];
    acc *= (1.f / 24.f);
  }
  apad[r * EP + tid] = __float2bfloat16(tid < Ed ? acc : 0.f);
}

// ---------------------------------------------------------------------------
// 2. fused GRU-weight prep (fp32 -> bf16): pad_wih f+b, whh f2bf f+b.
// grid 1728, block 512; total 884736 elements.
__global__ void prep1_kernel(const float* __restrict__ wih_f, const float* __restrict__ wih_b,
                             const float* __restrict__ whh_f, const float* __restrict__ whh_b,
                             __hip_bfloat16* __restrict__ wpadf, __hip_bfloat16* __restrict__ wpadb,
                             __hip_bfloat16* __restrict__ whhbf_f, __hip_bfloat16* __restrict__ whhbf_b) {
  int i = blockIdx.x * 512 + threadIdx.x;
  const int PW = 768 * EP;     // 245760
  const int WH = 768 * Hd;     // 196608
  if (i < 2 * PW) {
    const float* src = (i < PW) ? wih_f : wih_b;
    __hip_bfloat16* dst = (i < PW) ? wpadf : wpadb;
    int j = (i < PW) ? i : i - PW;
    int n = j / EP, k = j % EP;
    dst[j] = __float2bfloat16(k < Ed ? src[n * Ed + k] : 0.f);
  } else {
    int j = i - 2 * PW;
    const float* src = (j < WH) ? whh_f : whh_b;
    __hip_bfloat16* dst = (j < WH) ? whhbf_f : whhbf_b;
    int k = (j < WH) ? j : j - WH;
    dst[k] = __float2bfloat16(src[k]);
  }
}

// ---------------------------------------------------------------------------
// 3. MFMA GEMM: C[M,N] = A[M,K] @ W[N,K]^T (+bias[n]); A,W bf16 row-major, C fp32.
__global__ __launch_bounds__(256) void gemm_xwt_kernel(
    const __hip_bfloat16* __restrict__ A, int lda,
    const __hip_bfloat16* __restrict__ W, int ldw,
    float* __restrict__ C, int ldc,
    int M, int N, int K,
    const float* __restrict__ bias) {
  __shared__ unsigned short la[64][32];
  __shared__ unsigned short lb[64][32];
  const int tid = threadIdx.x;
  const int m0 = blockIdx.x * 64, n0 = blockIdx.y * 64;
  const int lane = tid & 63, wid = tid >> 6;
  const int wm = (wid >> 1) * 32, wn = (wid & 1) * 32;
  const int lrow = tid >> 2, lcol = (tid & 3) * 8;
  f32x4 acc00 = {0.f, 0.f, 0.f, 0.f}, acc01 = {0.f, 0.f, 0.f, 0.f};
  f32x4 acc10 = {0.f, 0.f, 0.f, 0.f}, acc11 = {0.f, 0.f, 0.f, 0.f};
  int arow = m0 + lrow; if (arow > M - 1) arow = M - 1;
  const int brow = n0 + lrow;
  const int fr = lane & 15, fq = (lane >> 4) * 8;
  for (int k0 = 0; k0 < K; k0 += 32) {
    uint4 av = *(const uint4*)(A + (size_t)arow * lda + k0 + lcol);
    uint4 bv = *(const uint4*)(W + (size_t)brow * ldw + k0 + lcol);
    *(uint4*)(&la[lrow][lcol]) = av;
    *(uint4*)(&lb[lrow][lcol]) = bv;
    __syncthreads();
    short8 a0 = *(const short8*)(&la[wm + fr][fq]);
    short8 a1 = *(const short8*)(&la[wm + 16 + fr][fq]);
    short8 b0 = *(const short8*)(&lb[wn + fr][fq]);
    short8 b1 = *(const short8*)(&lb[wn + 16 + fr][fq]);
    acc00 = __builtin_amdgcn_mfma_f32_16x16x32_bf16(a0, b0, acc00, 0, 0, 0);
    acc01 = __builtin_amdgcn_mfma_f32_16x16x32_bf16(a0, b1, acc01, 0, 0, 0);
    acc10 = __builtin_amdgcn_mfma_f32_16x16x32_bf16(a1, b0, acc10, 0, 0, 0);
    acc11 = __builtin_amdgcn_mfma_f32_16x16x32_bf16(a1, b1, acc11, 0, 0, 0);
    __syncthreads();
  }
  const int rq = (lane >> 4) * 4;
  f32x4 accs[2][2] = {{acc00, acc01}, {acc10, acc11}};
  for (int i = 0; i < 2; ++i)
    for (int j = 0; j < 2; ++j) {
      int n = n0 + wn + j * 16 + fr;
      float bv = bias ? bias[n] : 0.f;
      for (int r2 = 0; r2 < 4; ++r2) {
        int m = m0 + wm + i * 16 + rq + r2;
        if (m < M) C[(size_t)m * ldc + n] = accs[i][j][r2] + bv;
      }
    }
}

// ---------------------------------------------------------------------------
// 4. Persistent-weight MFMA GRU (r8 structure, at its per-CU MFMA floor) with
// FUSED attention-weight packing on otherwise-idle CUs.
// Blocks [0,64): GRU recurrence (dir=blk>>5, b=blk&31), block 512.
// Blocks [64,384): build Wpack1/Wpack2 bf16 [1280][512] while the GRU runs:
//   Wpack1[n][k] = n<1024 ? w_att[k][n]      : w_dna[512+k][n-1024]   (PD/RT)
//   Wpack2[n][k] = n<1024 ? w_att[512+k][n]  : w_dna[k][n-1024]       (QU)
__global__ __launch_bounds__(512, 2) void gru_mfma_kernel(
    const float* __restrict__ gi_f, const float* __restrict__ gi_b,
    const __hip_bfloat16* __restrict__ whhbf_f, const __hip_bfloat16* __restrict__ whhbf_b,
    const float* __restrict__ bhh_f, const float* __restrict__ bhh_b,
    float* __restrict__ sent_rep, __hip_bfloat16* __restrict__ sent_rep_bf,
    float* __restrict__ hT_f, float* __restrict__ hT_b,
    const float* __restrict__ w_att, const float* __restrict__ w_dna,
    __hip_bfloat16* __restrict__ wpack1, __hip_bfloat16* __restrict__ wpack2) {
  __shared__ float gi_lds[2][8][768];          // 49152 B
  __shared__ __hip_bfloat16 h_bf[256];         // 512 B (single live h row)
  __shared__ float gh[768];                    // 3072 B
  __shared__ float stg32[8][256];              // 8192 B
  const int blk = blockIdx.x;
  const int tid = threadIdx.x;

  if (blk >= 64) {
    // ---- fused weight-pack branch (no barriers, no LDS) ----
    const size_t q = (size_t)(blk - 64) * 512 + tid;
    size_t flat = q * 8;                        // [0, 1310720)
    const size_t HALF = (size_t)1280 * 512;     // 655360
    const bool second = flat >= HALF;
    size_t r = second ? flat - HALF : flat;
    int n = (int)(r >> 9), k0 = (int)(r & 511);
    __hip_bfloat16* dst = second ? wpack2 : wpack1;
#pragma unroll
    for (int j = 0; j < 8; ++j) {
      int k = k0 + j;
      float v;
      if (!second)
        v = (n < 1024) ? w_att[(size_t)k * 1024 + n]
                       : w_dna[(size_t)(512 + k) * 256 + (n - 1024)];
      else
        v = (n < 1024) ? w_att[(size_t)(512 + k) * 1024 + n]
                       : w_dna[(size_t)k * 256 + (n - 1024)];
      dst[(size_t)n * 512 + k] = __float2bfloat16(v);
    }
    return;
  }

  // ---- GRU recurrence branch (identical to r8 passing kernel) ----
  const int dir = blk >> 5, b = blk & 31;
  const int lane = tid & 63, w = tid >> 6;
  const float* gi = dir ? gi_b : gi_f;
  const __hip_bfloat16* whh = dir ? whhbf_b : whhbf_f;
  const float* bhh = dir ? bhh_b : bhh_f;

  if (tid < 256) h_bf[tid] = __float2bfloat16(0.f);

  short8 bfrag[6][8];
  {
    const int n0 = w * 96 + (lane & 15);
    const int kq = (lane >> 4) * 8;
#pragma unroll
    for (int nt = 0; nt < 6; ++nt)
#pragma unroll
      for (int kt = 0; kt < 8; ++kt)
        bfrag[nt][kt] = *(const short8*)(whh + (size_t)(n0 + nt * 16) * 256 + kt * 32 + kq);
  }
  float bhr = 0.f, bhz = 0.f, bhn = 0.f, hprev = 0.f;
  if (tid < 256) { bhr = bhh[tid]; bhz = bhh[256 + tid]; bhn = bhh[512 + tid]; }

  auto burst = [&](int tstart, int buf) {
#pragma unroll
    for (int i = 0; i < 3; ++i) {
      int idx = tid + i * 512;               // 0..1535 = 8 rows x 192 float4
      int u = idx / 192;
      int c4 = (idx - u * 192) * 4;
      int s = dir ? (255 - (tstart + u)) : (tstart + u);
      float4 v = *(const float4*)(gi + (size_t)(((b << 8) + s) * 768 + c4));
      *(float4*)(&gi_lds[buf][u][c4]) = v;
    }
  };
  burst(0, 0);
  __syncthreads();

  const int c = lane & 15;
  const int kq = (lane >> 4) * 8;
  const short8 zero8 = {0, 0, 0, 0, 0, 0, 0, 0};

  for (int t = 0; t < Sd; ++t) {
    if ((t & 7) == 0 && t + 8 < Sd) burst(t + 8, ((t >> 3) + 1) & 1);
    f32x4 acc[6];
#pragma unroll
    for (int nt = 0; nt < 6; ++nt) acc[nt] = (f32x4){0.f, 0.f, 0.f, 0.f};
#pragma unroll
    for (int kt = 0; kt < 8; ++kt) {
      short8 av = *(const short8*)(&h_bf[kt * 32 + kq]);
      if (c != 0) av = zero8;
#pragma unroll
      for (int nt = 0; nt < 6; ++nt)
        acc[nt] = __builtin_amdgcn_mfma_f32_16x16x32_bf16(av, bfrag[nt][kt], acc[nt], 0, 0, 0);
    }
    if (lane < 16) {
#pragma unroll
      for (int nt = 0; nt < 6; ++nt)
        gh[w * 96 + nt * 16 + lane] = acc[nt][0];
    }
    __syncthreads();
    if (tid < 256) {
      const float* gl = gi_lds[(t >> 3) & 1][t & 7];
      float rr = fsigm(gl[tid] + gh[tid] + bhr);
      float zz = fsigm(gl[256 + tid] + gh[256 + tid] + bhz);
      float nn = ftanh(gl[512 + tid] + rr * (gh[512 + tid] + bhn));
      float hn = (1.f - zz) * nn + zz * hprev;
      hprev = hn;
      h_bf[tid] = __float2bfloat16(hn);
      stg32[t & 7][tid] = hn;
    }
    __syncthreads();
    if ((t & 7) == 7) {
      const int base = t - 7;
#pragma unroll
      for (int i = 0; i < 4; ++i) {
        int idx = tid + i * 512;
        int u = idx >> 8, d = idx & 255;
        int sg = dir ? (255 - (base + u)) : (base + u);
        size_t rowg = (size_t)((b << 8) + sg);
        int col = dir ? (256 + d) : d;
        float v = stg32[u][d];
        sent_rep[rowg * 512 + col] = v;
        sent_rep_bf[rowg * 512 + col] = __float2bfloat16(v);
      }
    }
  }
  if (tid < 256) (dir ? hT_b : hT_f)[b * 256 + tid] = hprev;
}

// ---------------------------------------------------------------------------
// 5. doc_vec per torch view(B,2H) on stacked [2,B,H]. grid 32, block 512.
__global__ void docvec_kernel(const float* __restrict__ hTf, const float* __restrict__ hTb,
                              __hip_bfloat16* __restrict__ dv) {
  int b = blockIdx.x, jj = threadIdx.x;
  int idx = b * 512 + jj;
  int dsel = idx >> 13;            // /8192
  int rem = idx & 8191;
  int bp = rem >> 8, hp = rem & 255;
  float v = (dsel ? hTb : hTf)[bp * Hd + hp];
  dv[idx] = __float2bfloat16(v);
}

// 6. topic_mat via boundary differencing. grid 512 (b*16+t), block 256.
__global__ void topic_kernel(const int* __restrict__ tse, const float* __restrict__ sent_rep,
                             __hip_bfloat16* __restrict__ topic_bf) {
  int bt = blockIdx.x;
  int b = bt >> 4;
  int st = tse[bt * 2], en = tse[bt * 2 + 1];   // 1-indexed
  int dd = threadIdx.x;
  auto pad = [&](int i, int col) -> float {
    if (i < 1 || i > Sd) return 0.f;
    return sent_rep[((size_t)((b << 8) + (i - 1))) * 512 + col];
  };
  float fwd = pad(en, dd) - pad(st - 1, dd);
  float bwd = pad(st, Hd + dd) - pad(en + 1, Hd + dd);
  topic_bf[(size_t)bt * 512 + dd] = __float2bfloat16(fwd);
  topic_bf[(size_t)bt * 512 + Hd + dd] = __float2bfloat16(bwd);
}

// ---------------------------------------------------------------------------
// 7. attention scores. grid 8192 (b*256+s), block 256.
// QU rows are 1280 wide (Q = cols 0..1023); PD/RT rows 1280 (P/R = cols 0..1023).
__global__ void scores_kernel(const float* __restrict__ PD, const float* __restrict__ RT,
                              const float* __restrict__ QU, const float* __restrict__ v_att,
                              const int* __restrict__ tse,
                              float* __restrict__ dsc, float* __restrict__ tsc) {
  int r = blockIdx.x;
  int b = r >> 8, s = r & 255;
  int tid = threadIdx.x;
  int tsel = Td - 1;
  for (int t = 0; t < Td; ++t) {
    if (tse[(b * Td + t) * 2 + 1] >= s + 1) { tsel = t; break; }
  }
  const float* q = QU + (size_t)r * 1280;
  const float* p = PD + (size_t)b * 1280;
  const float* rr = RT + (size_t)(b * Td + tsel) * 1280;
  float accd = 0.f, acct = 0.f;
  for (int n = tid; n < 1024; n += 256) {
    float qv = q[n];
    float vv = v_att[n];
    accd += ftanh(p[n] + qv) * vv;
    acct += ftanh(rr[n] + qv) * vv;
  }
  __shared__ float s1[256], s2[256];
  s1[tid] = accd; s2[tid] = acct;
  __syncthreads();
  for (int off = 128; off > 0; off >>= 1) {
    if (tid < off) { s1[tid] += s1[tid + off]; s2[tid] += s2[tid + off]; }
    __syncthreads();
  }
  if (tid == 0) { dsc[r] = s1[0]; tsc[r] = s2[0]; }
}

// 8. softmax over s per batch (both score sets). grid 32, block 256.
__global__ void softmax_kernel(const float* __restrict__ dsc, const float* __restrict__ tsc,
                               float* __restrict__ dw, float* __restrict__ tw) {
  int b = blockIdx.x, s = threadIdx.x;
  __shared__ float red[256];
  for (int which = 0; which < 2; ++which) {
    const float* src = which ? tsc : dsc;
    float v = src[b * Sd + s];
    red[s] = v; __syncthreads();
    for (int off = 128; off > 0; off >>= 1) {
      if (s < off) red[s] = fmaxf(red[s], red[s + off]);
      __syncthreads();
    }
    float m = red[0]; __syncthreads();
    float e = __expf(v - m);
    red[s] = e; __syncthreads();
    for (int off = 128; off > 0; off >>= 1) {
      if (s < off) red[s] += red[s + off];
      __syncthreads();
    }
    float sum = red[0]; __syncthreads();
    (which ? tw : dw)[b * Sd + s] = e / sum;
  }
}

// 9. final head. grid 8192, block 256. OUTPUT IS FP32.
// U = QU cols 1024..1279; dvd = PD cols 1024..1279; tvd = RT cols 1024..1279.
__global__ void final_kernel(const float* __restrict__ QU, const float* __restrict__ PD,
                             const float* __restrict__ RT, const float* __restrict__ dw,
                             const float* __restrict__ tw, const float* __restrict__ b_dna,
                             const float* __restrict__ w_out,
                             const float* __restrict__ b_out,
                             const int* __restrict__ tse, float* __restrict__ out) {
  int r = blockIdx.x;
  int b = r >> 8, s = r & 255;
  int dd = threadIdx.x;
  int tsel = Td - 1;
  for (int t = 0; t < Td; ++t) {
    if (tse[(b * Td + t) * 2 + 1] >= s + 1) { tsel = t; break; }
  }
  float wdv = dw[b * Sd + s], wtv = tw[b * Sd + s];
  float x = QU[(size_t)r * 1280 + 1024 + dd] + wdv * PD[(size_t)b * 1280 + 1024 + dd] +
            wtv * RT[(size_t)(b * Td + tsel) * 1280 + 1024 + dd] + b_dna[dd];
  x = fmaxf(x, 0.f);
  float term = x * w_out[dd];
  __shared__ float red[256];
  red[dd] = term; __syncthreads();
  for (int off = 128; off > 0; off >>= 1) {
    if (dd < off) red[dd] += red[dd + off];
    __syncthreads();
  }
  if (dd == 0) out[r] = red[0] + b_out[0];
}

// ---------------------------------------------------------------------------
static void launch_gemm(const __hip_bfloat16* A, int lda, const __hip_bfloat16* W, int ldw,
                        float* C, int ldc, int M, int N, int K,
                        const float* bias, hipStream_t stream) {
  dim3 grid((M + 63) / 64, N / 64);
  gemm_xwt_kernel<<<grid, 256, 0, stream>>>(A, lda, W, ldw, C, ldc, M, N, K, bias);
}

extern "C" void kernel_launch(void* const* d_in, const int* in_sizes, int n_in,
                              void* d_out, int out_size, void* d_ws, size_t ws_size,
                              hipStream_t stream) {
  const int* word_ids = (const int*)d_in[0];
  const int* tse      = (const int*)d_in[1];
  const float* emb   = (const float*)d_in[2];
  const float* wih_f = (const float*)d_in[3];
  const float* whh_f = (const float*)d_in[4];
  const float* bih_f = (const float*)d_in[5];
  const float* bhh_f = (const float*)d_in[6];
  const float* wih_b = (const float*)d_in[7];
  const float* whh_b = (const float*)d_in[8];
  const float* bih_b = (const float*)d_in[9];
  const float* bhh_b = (const float*)d_in[10];
  const float* w_att = (const float*)d_in[11];
  const float* v_att = (const float*)d_in[12];
  const float* w_dna = (const float*)d_in[13];
  const float* b_dna = (const float*)d_in[14];
  const float* w_out = (const float*)d_in[15];
  const float* b_out = (const float*)d_in[16];
  float* out = (float*)d_out;
  char* ws = (char*)d_ws;

  const int M = Bd * Sd;  // 8192

  // workspace layout (bytes)
  size_t off = 0;
  auto alloc = [&](size_t sz) { size_t o = off; off += (sz + 255) & ~(size_t)255; return o; };
  size_t o_svbf   = alloc((size_t)M * EP * 2);          // A_pad bf16 [8192,320]
  size_t o_wpadf  = alloc((size_t)768 * EP * 2);
  size_t o_wpadb  = alloc((size_t)768 * EP * 2);
  size_t o_whhbf  = alloc((size_t)768 * Hd * 2 * 2);    // whh f+b bf16
  size_t o_wpack1 = alloc((size_t)1280 * 512 * 2);      // [W_att[:512];W_dna[512:]] ^T bf16
  size_t o_wpack2 = alloc((size_t)1280 * 512 * 2);      // [W_att[512:];W_dna[:512]] ^T bf16
  size_t o_hTf    = alloc((size_t)Bd * Hd * 4);
  size_t o_hTb    = alloc((size_t)Bd * Hd * 4);
  size_t o_dvbf   = alloc((size_t)Bd * 512 * 2);        // doc_vec bf16
  size_t o_topbf  = alloc((size_t)Bd * Td * 512 * 2);   // topic_mat bf16
  size_t o_PD     = alloc((size_t)Bd * 1280 * 4);       // [P | dvd]
  size_t o_RT     = alloc((size_t)Bd * Td * 1280 * 4);  // [R | tvd]
  size_t o_dsc    = alloc((size_t)Bd * Sd * 4);
  size_t o_tsc    = alloc((size_t)Bd * Sd * 4);
  size_t o_dw     = alloc((size_t)Bd * Sd * 4);
  size_t o_tw     = alloc((size_t)Bd * Sd * 4);
  size_t o_srep32 = alloc((size_t)M * 512 * 4);         // sent_rep fp32
  size_t o_srepbf = alloc((size_t)M * 512 * 2);         // sent_rep bf16
  size_t o_gif    = alloc((size_t)M * 768 * 4);         // gi fwd fp32
  size_t o_gib    = alloc((size_t)M * 768 * 4);         // gi bwd fp32
  // QU [8192,1280] f32 overlays the dead gi region after the GRU
  size_t o_QU = o_gif;
  (void)ws_size;

  __hip_bfloat16* svbf   = (__hip_bfloat16*)(ws + o_svbf);
  __hip_bfloat16* wpadf  = (__hip_bfloat16*)(ws + o_wpadf);
  __hip_bfloat16* wpadb  = (__hip_bfloat16*)(ws + o_wpadb);
  __hip_bfloat16* whhbf_f = (__hip_bfloat16*)(ws + o_whhbf);
  __hip_bfloat16* whhbf_b = whhbf_f + 768 * Hd;
  __hip_bfloat16* wpack1 = (__hip_bfloat16*)(ws + o_wpack1);
  __hip_bfloat16* wpack2 = (__hip_bfloat16*)(ws + o_wpack2);
  float* hTf = (float*)(ws + o_hTf);
  float* hTb = (float*)(ws + o_hTb);
  __hip_bfloat16* dvbf  = (__hip_bfloat16*)(ws + o_dvbf);
  __hip_bfloat16* topbf = (__hip_bfloat16*)(ws + o_topbf);
  float* PD  = (float*)(ws + o_PD);
  float* RT  = (float*)(ws + o_RT);
  float* dsc = (float*)(ws + o_dsc);
  float* tsc = (float*)(ws + o_tsc);
  float* dw  = (float*)(ws + o_dw);
  float* tw  = (float*)(ws + o_tw);
  float* srep32 = (float*)(ws + o_srep32);
  __hip_bfloat16* srepbf = (__hip_bfloat16*)(ws + o_srepbf);
  float* gif = (float*)(ws + o_gif);
  float* gib = (float*)(ws + o_gib);
  float* QU  = (float*)(ws + o_QU);

  // 1. sentence means -> padded bf16 activations
  sent_means_kernel<<<M, EP, 0, stream>>>(word_ids, emb, svbf);
  // 2. fused GRU weight prep
  prep1_kernel<<<1728, 512, 0, stream>>>(wih_f, wih_b, whh_f, whh_b,
                                         wpadf, wpadb, whhbf_f, whhbf_b);
  // 3. input projections gi = sv @ Wih^T + bih
  launch_gemm(svbf, EP, wpadf, EP, gif, 768, M, 768, EP, bih_f, stream);
  launch_gemm(svbf, EP, wpadb, EP, gib, 768, M, 768, EP, bih_b, stream);
  // 4. GRU recurrence + fused att/dna weight packing on idle CUs
  gru_mfma_kernel<<<384, 512, 0, stream>>>(gif, gib, whhbf_f, whhbf_b, bhh_f, bhh_b,
                                           srep32, srepbf, hTf, hTb,
                                           w_att, w_dna, wpack1, wpack2);
  // 5/6. doc_vec + topic_mat
  docvec_kernel<<<Bd, 512, 0, stream>>>(hTf, hTb, dvbf);
  topic_kernel<<<Bd * Td, 256, 0, stream>>>(tse, srep32, topbf);
  // 7. merged attention/dense GEMMs
  launch_gemm(srepbf, 512, wpack2, 512, QU, 1280, M, 1280, 512, nullptr, stream);
  launch_gemm(dvbf, 512, wpack1, 512, PD, 1280, Bd, 1280, 512, nullptr, stream);
  launch_gemm(topbf, 512, wpack1, 512, RT, 1280, Bd * Td, 1280, 512, nullptr, stream);
  // 8. scores + softmax
  scores_kernel<<<M, 256, 0, stream>>>(PD, RT, QU, v_att, tse, dsc, tsc);
  softmax_kernel<<<Bd, 256, 0, stream>>>(dsc, tsc, dw, tw);
  // 9. fused dense head -> logits (fp32)
  final_kernel<<<M, 256, 0, stream>>>(QU, PD, RT, dw, tw, b_dna, w_out, b_out, tse, out);
}